// Round 1
// baseline (1504.374 us; speedup 1.0000x reference)
//
#include <hip/hip_runtime.h>
#include <math.h>

#define C_IN 16

// ---------------- degree ----------------
__global__ __launch_bounds__(256) void deg_count_kernel(const int* __restrict__ dst, int E,
                                                        float* __restrict__ deg) {
    int e = blockIdx.x * 256 + threadIdx.x;
    if (e < E) unsafeAtomicAdd(&deg[dst[e]], 1.0f);
}

__global__ __launch_bounds__(256) void dinv_kernel(const float* __restrict__ deg,
                                                   float* __restrict__ dinv,
                                                   float* __restrict__ invdeg, int n) {
    int i = blockIdx.x * 256 + threadIdx.x;
    if (i < n) {
        float d = deg[i] + 1.0f;
        dinv[i] = rsqrtf(d);
        invdeg[i] = 1.0f / d;
    }
}

// ---------------- dense XW + self-loop init ----------------
// hs[i]  = (x_i @ W) * dinv[i]            (scatter source, pre-scaled by dinv[src])
// agg[i] = (x_i @ W) * invdeg[i] + b      (self-loop term + bias; scatter adds on top)
template<int CIN, int COUT, bool RELU_IN>
__global__ __launch_bounds__(256) void xw_kernel(const float* __restrict__ x,
                                                 const float* __restrict__ W,
                                                 const float* __restrict__ b,
                                                 const float* __restrict__ dinv,
                                                 const float* __restrict__ invdeg,
                                                 float* __restrict__ hs,
                                                 float* __restrict__ agg, int n) {
    __shared__ float Ws[CIN * COUT];
    __shared__ float bs[COUT];
    for (int idx = threadIdx.x; idx < CIN * COUT; idx += 256) Ws[idx] = W[idx];
    if (threadIdx.x < COUT) bs[threadIdx.x] = b[threadIdx.x];
    __syncthreads();

    int i = blockIdx.x * 256 + threadIdx.x;
    if (i >= n) return;

    float xr[CIN];
    const float4* xv = reinterpret_cast<const float4*>(x + (size_t)i * CIN);
    #pragma unroll
    for (int k4 = 0; k4 < CIN / 4; ++k4) {
        float4 v = xv[k4];
        xr[k4*4+0] = v.x; xr[k4*4+1] = v.y; xr[k4*4+2] = v.z; xr[k4*4+3] = v.w;
    }
    if (RELU_IN) {
        #pragma unroll
        for (int k = 0; k < CIN; ++k) xr[k] = fmaxf(xr[k], 0.0f);
    }

    float di = dinv[i], idg = invdeg[i];
    float4* hsv = reinterpret_cast<float4*>(hs + (size_t)i * COUT);
    float4* agv = reinterpret_cast<float4*>(agg + (size_t)i * COUT);

    #pragma unroll 1
    for (int c4 = 0; c4 < COUT / 4; ++c4) {
        float a0 = 0.f, a1 = 0.f, a2 = 0.f, a3 = 0.f;
        #pragma unroll
        for (int k = 0; k < CIN; ++k) {
            const float4 w = *reinterpret_cast<const float4*>(&Ws[k * COUT + c4 * 4]);
            float xk = xr[k];
            a0 = fmaf(xk, w.x, a0);
            a1 = fmaf(xk, w.y, a1);
            a2 = fmaf(xk, w.z, a2);
            a3 = fmaf(xk, w.w, a3);
        }
        float4 hv, av;
        const float4 bv = *reinterpret_cast<const float4*>(&bs[c4 * 4]);
        hv.x = a0 * di; hv.y = a1 * di; hv.z = a2 * di; hv.w = a3 * di;
        av.x = fmaf(a0, idg, bv.x);
        av.y = fmaf(a1, idg, bv.y);
        av.z = fmaf(a2, idg, bv.z);
        av.w = fmaf(a3, idg, bv.w);
        hsv[c4] = hv;
        agv[c4] = av;
    }
}

// ---------------- edge scatter: agg[dst] += hs[src] * dinv[dst] ----------------
template<int COUT>
__global__ __launch_bounds__(256) void scatter_kernel(const int* __restrict__ src,
                                                      const int* __restrict__ dst,
                                                      const float* __restrict__ hs,
                                                      const float* __restrict__ dinv,
                                                      float* __restrict__ agg, int E) {
    constexpr int TPE = COUT / 4;          // threads per edge, each handles a float4
    long long tid = (long long)blockIdx.x * 256 + threadIdx.x;
    long long total = (long long)E * TPE;
    if (tid >= total) return;
    int e = (int)(tid / TPE);
    int q = (int)(tid % TPE);
    int s = src[e], d = dst[e];
    float sc = dinv[d];
    const float4 v = *reinterpret_cast<const float4*>(&hs[(size_t)s * COUT + q * 4]);
    float* out = &agg[(size_t)d * COUT + q * 4];
    unsafeAtomicAdd(out + 0, v.x * sc);
    unsafeAtomicAdd(out + 1, v.y * sc);
    unsafeAtomicAdd(out + 2, v.z * sc);
    unsafeAtomicAdd(out + 3, v.w * sc);
}

// ---------------- MLP head, j-split partial ----------------
// acc[i] += sum_{j in [j0,j0+256)} relu( relu(agg3_i) . Wf1[:,j] + bf1[j] ) * Wf2[j]
__global__ __launch_bounds__(256) void mlp_partial_kernel(const float* __restrict__ agg3,
                                                          const float* __restrict__ Wf1,
                                                          const float* __restrict__ bf1,
                                                          const float* __restrict__ Wf2,
                                                          float* __restrict__ acc_out, int n) {
    constexpr int JC = 256;
    __shared__ float Wl[32 * JC];     // [k][jj], k-major: coalesced load, broadcast read
    __shared__ float b1s[JC];
    __shared__ float w2s[JC];
    const int j0 = blockIdx.y * JC;

    for (int idx = threadIdx.x; idx < 32 * JC; idx += 256) {
        int k = idx / JC, jj = idx % JC;   // idx%256 == threadIdx.x -> coalesced global read
        Wl[idx] = Wf1[k * 1024 + j0 + jj];
    }
    if (threadIdx.x < JC) {
        b1s[threadIdx.x] = bf1[j0 + threadIdx.x];
        w2s[threadIdx.x] = Wf2[j0 + threadIdx.x];
    }
    __syncthreads();

    int i = blockIdx.x * 256 + threadIdx.x;
    if (i >= n) return;

    float t[32];
    const float4* av = reinterpret_cast<const float4*>(agg3 + (size_t)i * 32);
    #pragma unroll
    for (int k4 = 0; k4 < 8; ++k4) {
        float4 v = av[k4];
        t[k4*4+0] = fmaxf(v.x, 0.f);
        t[k4*4+1] = fmaxf(v.y, 0.f);
        t[k4*4+2] = fmaxf(v.z, 0.f);
        t[k4*4+3] = fmaxf(v.w, 0.f);
    }

    float acc = 0.0f;
    #pragma unroll 1
    for (int jj = 0; jj < JC; jj += 4) {
        float s0 = b1s[jj + 0];
        float s1 = b1s[jj + 1];
        float s2 = b1s[jj + 2];
        float s3 = b1s[jj + 3];
        #pragma unroll
        for (int k = 0; k < 32; ++k) {
            const float4 w = *reinterpret_cast<const float4*>(&Wl[k * JC + jj]);
            float tk = t[k];
            s0 = fmaf(tk, w.x, s0);
            s1 = fmaf(tk, w.y, s1);
            s2 = fmaf(tk, w.z, s2);
            s3 = fmaf(tk, w.w, s3);
        }
        acc = fmaf(fmaxf(s0, 0.f), w2s[jj + 0], acc);
        acc = fmaf(fmaxf(s1, 0.f), w2s[jj + 1], acc);
        acc = fmaf(fmaxf(s2, 0.f), w2s[jj + 2], acc);
        acc = fmaf(fmaxf(s3, 0.f), w2s[jj + 3], acc);
    }
    unsafeAtomicAdd(&acc_out[i], acc);
}

__global__ __launch_bounds__(256) void sigmoid_kernel(const float* __restrict__ acc,
                                                      const float* __restrict__ bf2,
                                                      float* __restrict__ out, int n) {
    int i = blockIdx.x * 256 + threadIdx.x;
    if (i < n) {
        float z = acc[i] + bf2[0];
        out[i] = 1.0f / (1.0f + expf(-z));
    }
}

extern "C" void kernel_launch(void* const* d_in, const int* in_sizes, int n_in,
                              void* d_out, int out_size, void* d_ws, size_t ws_size,
                              hipStream_t stream) {
    const float* x    = (const float*)d_in[0];
    const int*   ei   = (const int*)d_in[1];
    const float* W1   = (const float*)d_in[2];
    const float* b1   = (const float*)d_in[3];
    const float* W2   = (const float*)d_in[4];
    const float* b2   = (const float*)d_in[5];
    const float* W3   = (const float*)d_in[6];
    const float* b3   = (const float*)d_in[7];
    const float* Wf1  = (const float*)d_in[8];
    const float* bf1  = (const float*)d_in[9];
    const float* Wf2  = (const float*)d_in[10];
    const float* bf2  = (const float*)d_in[11];
    float* out = (float*)d_out;

    const int n = in_sizes[0] / C_IN;          // 50000
    const int E = in_sizes[1] / 2;             // 800000
    const int* src = ei;
    const int* dst = ei + E;

    // workspace layout (floats)
    float* ws = (float*)d_ws;
    float* deg    = ws;                         // [n]
    float* accml  = ws + (size_t)n;             // [n]
    float* dinv   = ws + (size_t)2 * n;         // [n]
    float* invdeg = ws + (size_t)3 * n;         // [n]
    float* agg1   = ws + (size_t)4 * n;         // [n*32]
    float* hs1    = ws + (size_t)36 * n;        // [n*32]
    float* agg2   = ws + (size_t)68 * n;        // [n*64]
    float* hs2    = ws + (size_t)132 * n;       // [n*64]
    float* agg3   = ws + (size_t)196 * n;       // [n*32]
    float* hs3    = ws + (size_t)228 * n;       // [n*32]
    (void)ws_size; (void)n_in; (void)out_size; (void)hs3;

    const int nb_n = (n + 255) / 256;           // node blocks
    const int nb_e = (E + 255) / 256;

    // zero deg + mlp accumulator (adjacent regions)
    hipMemsetAsync(deg, 0, (size_t)2 * n * sizeof(float), stream);

    deg_count_kernel<<<nb_e, 256, 0, stream>>>(dst, E, deg);
    dinv_kernel<<<nb_n, 256, 0, stream>>>(deg, dinv, invdeg, n);

    // layer 1: 16 -> 32
    xw_kernel<16, 32, false><<<nb_n, 256, 0, stream>>>(x, W1, b1, dinv, invdeg, hs1, agg1, n);
    scatter_kernel<32><<<(int)(((long long)E * 8 + 255) / 256), 256, 0, stream>>>(src, dst, hs1, dinv, agg1, E);

    // layer 2: 32 -> 64
    xw_kernel<32, 64, true><<<nb_n, 256, 0, stream>>>(agg1, W2, b2, dinv, invdeg, hs2, agg2, n);
    scatter_kernel<64><<<(int)(((long long)E * 16 + 255) / 256), 256, 0, stream>>>(src, dst, hs2, dinv, agg2, E);

    // layer 3: 64 -> 32
    xw_kernel<64, 32, true><<<nb_n, 256, 0, stream>>>(agg2, W3, b3, dinv, invdeg, hs3, agg3, n);
    scatter_kernel<32><<<(int)(((long long)E * 8 + 255) / 256), 256, 0, stream>>>(src, dst, hs3, dinv, agg3, E);

    // MLP head: 32 -> 1024 -> 1, j-split into 4 partials
    dim3 mgrid(nb_n, 4);
    mlp_partial_kernel<<<mgrid, 256, 0, stream>>>(agg3, Wf1, bf1, Wf2, accml, n);
    sigmoid_kernel<<<nb_n, 256, 0, stream>>>(accml, bf2, out, n);
}

// Round 3
// 277.726 us; speedup vs baseline: 5.4168x; 5.4168x over previous
//
#include <hip/hip_runtime.h>
#include <math.h>

#define C_IN 16
#define NTH 256

// ---------------- degree count (int) ----------------
__global__ __launch_bounds__(NTH) void count_kernel(const int* __restrict__ dst, int E,
                                                    int* __restrict__ cnt) {
    int e = blockIdx.x * NTH + threadIdx.x;
    if (e < E) atomicAdd(&cnt[dst[e]], 1);
}

__global__ __launch_bounds__(NTH) void dinv_kernel(const int* __restrict__ cnt,
                                                   float* __restrict__ dinv,
                                                   float* __restrict__ invdeg, int n) {
    int i = blockIdx.x * NTH + threadIdx.x;
    if (i < n) {
        float d = (float)cnt[i] + 1.0f;
        dinv[i] = rsqrtf(d);
        invdeg[i] = 1.0f / d;
    }
}

// ---------------- 3-pass exclusive scan over cnt -> row_ptr, cursor ----------------
__global__ __launch_bounds__(NTH) void scan1_kernel(const int* __restrict__ cnt, int n,
                                                    int* __restrict__ bsum) {
    __shared__ int s[NTH];
    int i = blockIdx.x * NTH + threadIdx.x;
    s[threadIdx.x] = (i < n) ? cnt[i] : 0;
    __syncthreads();
    for (int off = NTH / 2; off > 0; off >>= 1) {
        if (threadIdx.x < off) s[threadIdx.x] += s[threadIdx.x + off];
        __syncthreads();
    }
    if (threadIdx.x == 0) bsum[blockIdx.x] = s[0];
}

__global__ __launch_bounds__(NTH) void scan2_kernel(int* __restrict__ bsum, int nb) {
    __shared__ int s[NTH];
    int base = 0;
    for (int c = 0; c < nb; c += NTH) {
        int idx = c + threadIdx.x;
        int v = (idx < nb) ? bsum[idx] : 0;
        s[threadIdx.x] = v;
        __syncthreads();
        for (int off = 1; off < NTH; off <<= 1) {
            int x = (threadIdx.x >= off) ? s[threadIdx.x - off] : 0;
            __syncthreads();
            s[threadIdx.x] += x;
            __syncthreads();
        }
        if (idx < nb) bsum[idx] = base + s[threadIdx.x] - v;  // exclusive
        int tot = s[NTH - 1];
        __syncthreads();
        base += tot;
    }
}

__global__ __launch_bounds__(NTH) void scan3_kernel(const int* __restrict__ cnt,
                                                    const int* __restrict__ bsum, int n,
                                                    int* __restrict__ row,
                                                    int* __restrict__ cur) {
    __shared__ int s[NTH];
    int i = blockIdx.x * NTH + threadIdx.x;
    int v = (i < n) ? cnt[i] : 0;
    s[threadIdx.x] = v;
    __syncthreads();
    for (int off = 1; off < NTH; off <<= 1) {
        int x = (threadIdx.x >= off) ? s[threadIdx.x - off] : 0;
        __syncthreads();
        s[threadIdx.x] += x;
        __syncthreads();
    }
    if (i < n) {
        int excl = bsum[blockIdx.x] + s[threadIdx.x] - v;
        row[i] = excl;
        cur[i] = excl;
        if (i == n - 1) row[n] = excl + v;
    }
}

__global__ __launch_bounds__(NTH) void fill_kernel(const int* __restrict__ src,
                                                   const int* __restrict__ dst, int E,
                                                   int* __restrict__ cur,
                                                   int* __restrict__ csr) {
    int e = blockIdx.x * NTH + threadIdx.x;
    if (e < E) {
        int p = atomicAdd(&cur[dst[e]], 1);
        csr[p] = src[e];
    }
}

// ---------------- prescale: xs = x * dinv[i]  (C=16, one float4/thread) ----------------
__global__ __launch_bounds__(NTH) void prescale16_kernel(const float* __restrict__ x,
                                                         const float* __restrict__ dinv,
                                                         float* __restrict__ xs, int n) {
    int idx = blockIdx.x * NTH + threadIdx.x;   // float4 index; 4 per node
    if (idx >= n * 4) return;
    int i = idx >> 2;
    float4 v = reinterpret_cast<const float4*>(x)[idx];
    float d = dinv[i];
    v.x *= d; v.y *= d; v.z *= d; v.w *= d;
    reinterpret_cast<float4*>(xs)[idx] = v;
}

// ---------------- CSR gather: out[i] = dinv[i]*sum xs[src] + invdeg[i]*self[i] (+b, relu) --
template<int C, bool FINAL>
__global__ __launch_bounds__(NTH) void gather_kernel(const int* __restrict__ row,
                                                     const int* __restrict__ csr,
                                                     const float* __restrict__ xs,
                                                     const float* __restrict__ self,
                                                     const float* __restrict__ dinv,
                                                     const float* __restrict__ invdeg,
                                                     const float* __restrict__ bias,
                                                     float* __restrict__ out, int n) {
    constexpr int G = C / 4;                    // threads per node
    int i = blockIdx.x * (NTH / G) + threadIdx.x / G;
    int q = threadIdx.x % G;
    if (i >= n) return;
    int r0 = row[i], r1 = row[i + 1];
    float4 acc = make_float4(0.f, 0.f, 0.f, 0.f);
    int e = r0;
    for (; e + 1 < r1; e += 2) {
        int s0 = csr[e], s1 = csr[e + 1];
        float4 v0 = *reinterpret_cast<const float4*>(xs + (size_t)s0 * C + q * 4);
        float4 v1 = *reinterpret_cast<const float4*>(xs + (size_t)s1 * C + q * 4);
        acc.x += v0.x + v1.x; acc.y += v0.y + v1.y;
        acc.z += v0.z + v1.z; acc.w += v0.w + v1.w;
    }
    if (e < r1) {
        int s0 = csr[e];
        float4 v0 = *reinterpret_cast<const float4*>(xs + (size_t)s0 * C + q * 4);
        acc.x += v0.x; acc.y += v0.y; acc.z += v0.z; acc.w += v0.w;
    }
    float di = dinv[i], idg = invdeg[i];
    float4 sv = *reinterpret_cast<const float4*>(self + (size_t)i * C + q * 4);
    float4 o;
    o.x = fmaf(acc.x, di, sv.x * idg);
    o.y = fmaf(acc.y, di, sv.y * idg);
    o.z = fmaf(acc.z, di, sv.z * idg);
    o.w = fmaf(acc.w, di, sv.w * idg);
    if (FINAL) {
        const float4 b = *reinterpret_cast<const float4*>(bias + q * 4);
        o.x = fmaxf(o.x + b.x, 0.f);
        o.y = fmaxf(o.y + b.y, 0.f);
        o.z = fmaxf(o.z + b.z, 0.f);
        o.w = fmaxf(o.w + b.w, 0.f);
    }
    *reinterpret_cast<float4*>(out + (size_t)i * C + q * 4) = o;
}

// ---------------- dense transform: h = [relu](g @ W + b); optional hsc = h * dinv ------
template<int CIN, int COUT, bool BIASRELU, bool WSC>
__global__ __launch_bounds__(NTH) void transform_kernel(const float* __restrict__ g,
                                                        const float* __restrict__ W,
                                                        const float* __restrict__ b,
                                                        const float* __restrict__ dinv,
                                                        float* __restrict__ h,
                                                        float* __restrict__ hsc, int n) {
    __shared__ float Ws[CIN * COUT];
    __shared__ float bs[COUT];
    for (int idx = threadIdx.x; idx < CIN * COUT; idx += NTH) Ws[idx] = W[idx];
    if (BIASRELU && threadIdx.x < COUT) bs[threadIdx.x] = b[threadIdx.x];
    __syncthreads();

    int i = blockIdx.x * NTH + threadIdx.x;
    if (i >= n) return;

    float xr[CIN];
    const float4* xv = reinterpret_cast<const float4*>(g + (size_t)i * CIN);
    #pragma unroll
    for (int k4 = 0; k4 < CIN / 4; ++k4) {
        float4 v = xv[k4];
        xr[k4*4+0] = v.x; xr[k4*4+1] = v.y; xr[k4*4+2] = v.z; xr[k4*4+3] = v.w;
    }

    float di = WSC ? dinv[i] : 0.f;
    float4* hv = reinterpret_cast<float4*>(h + (size_t)i * COUT);
    float4* hscv = WSC ? reinterpret_cast<float4*>(hsc + (size_t)i * COUT) : nullptr;

    #pragma unroll 1
    for (int c4 = 0; c4 < COUT / 4; ++c4) {
        float a0 = 0.f, a1 = 0.f, a2 = 0.f, a3 = 0.f;
        #pragma unroll
        for (int k = 0; k < CIN; ++k) {
            const float4 w = *reinterpret_cast<const float4*>(&Ws[k * COUT + c4 * 4]);
            float xk = xr[k];
            a0 = fmaf(xk, w.x, a0);
            a1 = fmaf(xk, w.y, a1);
            a2 = fmaf(xk, w.z, a2);
            a3 = fmaf(xk, w.w, a3);
        }
        if (BIASRELU) {
            const float4 bv = *reinterpret_cast<const float4*>(&bs[c4 * 4]);
            a0 = fmaxf(a0 + bv.x, 0.f);
            a1 = fmaxf(a1 + bv.y, 0.f);
            a2 = fmaxf(a2 + bv.z, 0.f);
            a3 = fmaxf(a3 + bv.w, 0.f);
        }
        float4 o; o.x = a0; o.y = a1; o.z = a2; o.w = a3;
        hv[c4] = o;
        if (WSC) {
            float4 s; s.x = a0 * di; s.y = a1 * di; s.z = a2 * di; s.w = a3 * di;
            hscv[c4] = s;
        }
    }
}

// ---------------- MLP head, j-split partial ----------------
__global__ __launch_bounds__(NTH) void mlp_partial_kernel(const float* __restrict__ h3,
                                                          const float* __restrict__ Wf1,
                                                          const float* __restrict__ bf1,
                                                          const float* __restrict__ Wf2,
                                                          float* __restrict__ acc_out, int n) {
    constexpr int JC = 256;
    __shared__ float Wl[32 * JC];
    __shared__ float b1s[JC];
    __shared__ float w2s[JC];
    const int j0 = blockIdx.y * JC;

    for (int idx = threadIdx.x; idx < 32 * JC; idx += NTH) {
        int k = idx / JC, jj = idx % JC;
        Wl[idx] = Wf1[k * 1024 + j0 + jj];
    }
    if (threadIdx.x < JC) {
        b1s[threadIdx.x] = bf1[j0 + threadIdx.x];
        w2s[threadIdx.x] = Wf2[j0 + threadIdx.x];
    }
    __syncthreads();

    int i = blockIdx.x * NTH + threadIdx.x;
    if (i >= n) return;

    float t[32];
    const float4* av = reinterpret_cast<const float4*>(h3 + (size_t)i * 32);
    #pragma unroll
    for (int k4 = 0; k4 < 8; ++k4) {
        float4 v = av[k4];
        t[k4*4+0] = v.x; t[k4*4+1] = v.y; t[k4*4+2] = v.z; t[k4*4+3] = v.w;
    }

    float acc = 0.0f;
    #pragma unroll 1
    for (int jj = 0; jj < JC; jj += 4) {
        float s0 = b1s[jj + 0];
        float s1 = b1s[jj + 1];
        float s2 = b1s[jj + 2];
        float s3 = b1s[jj + 3];
        #pragma unroll
        for (int k = 0; k < 32; ++k) {
            const float4 w = *reinterpret_cast<const float4*>(&Wl[k * JC + jj]);
            float tk = t[k];
            s0 = fmaf(tk, w.x, s0);
            s1 = fmaf(tk, w.y, s1);
            s2 = fmaf(tk, w.z, s2);
            s3 = fmaf(tk, w.w, s3);
        }
        acc = fmaf(fmaxf(s0, 0.f), w2s[jj + 0], acc);
        acc = fmaf(fmaxf(s1, 0.f), w2s[jj + 1], acc);
        acc = fmaf(fmaxf(s2, 0.f), w2s[jj + 2], acc);
        acc = fmaf(fmaxf(s3, 0.f), w2s[jj + 3], acc);
    }
    unsafeAtomicAdd(&acc_out[i], acc);
}

__global__ __launch_bounds__(NTH) void sigmoid_kernel(const float* __restrict__ acc,
                                                      const float* __restrict__ bf2,
                                                      float* __restrict__ out, int n) {
    int i = blockIdx.x * NTH + threadIdx.x;
    if (i < n) {
        float z = acc[i] + bf2[0];
        out[i] = 1.0f / (1.0f + expf(-z));
    }
}

extern "C" void kernel_launch(void* const* d_in, const int* in_sizes, int n_in,
                              void* d_out, int out_size, void* d_ws, size_t ws_size,
                              hipStream_t stream) {
    const float* x    = (const float*)d_in[0];
    const int*   ei   = (const int*)d_in[1];
    const float* W1   = (const float*)d_in[2];
    const float* b1   = (const float*)d_in[3];
    const float* W2   = (const float*)d_in[4];
    const float* b2   = (const float*)d_in[5];
    const float* W3   = (const float*)d_in[6];
    const float* b3   = (const float*)d_in[7];
    const float* Wf1  = (const float*)d_in[8];
    const float* bf1  = (const float*)d_in[9];
    const float* Wf2  = (const float*)d_in[10];
    const float* bf2  = (const float*)d_in[11];
    float* out = (float*)d_out;

    const int n = in_sizes[0] / C_IN;          // 50000
    const int E = in_sizes[1] / 2;             // 800000
    const int* src = ei;
    const int* dst = ei + E;

    // ---- workspace layout ----
    float* ws = (float*)d_ws;
    float* dinv   = ws;                          // [n]
    float* invdeg = ws + (size_t)n;              // [n]
    float* accml  = ws + (size_t)2 * n;          // [n]
    float* buf1   = ws + (size_t)3 * n;          // [64n]
    float* buf2   = ws + (size_t)67 * n;         // [64n]
    float* buf3   = ws + (size_t)131 * n;        // [32n]
    int*   iw     = (int*)(ws + (size_t)163 * n);
    int*   cnt    = iw;                          // [n]
    int*   row    = iw + (size_t)n;              // [n+1]
    int*   cur    = iw + (size_t)2 * n + 1;      // [n]
    int*   csr    = iw + (size_t)3 * n + 1;      // [E]
    int*   bsums  = iw + (size_t)3 * n + 1 + E;  // [nb_n] — DISJOINT from cur (round-2 race fix)
    (void)ws_size; (void)n_in; (void)out_size;

    const int nb_n = (n + NTH - 1) / NTH;        // 196
    const int nb_e = (E + NTH - 1) / NTH;        // 3125

    hipMemsetAsync(accml, 0, (size_t)n * sizeof(float), stream);
    hipMemsetAsync(cnt, 0, (size_t)n * sizeof(int), stream);

    // degree + CSR build
    count_kernel<<<nb_e, NTH, 0, stream>>>(dst, E, cnt);
    dinv_kernel<<<nb_n, NTH, 0, stream>>>(cnt, dinv, invdeg, n);
    scan1_kernel<<<nb_n, NTH, 0, stream>>>(cnt, n, bsums);
    scan2_kernel<<<1, NTH, 0, stream>>>(bsums, nb_n);
    scan3_kernel<<<nb_n, NTH, 0, stream>>>(cnt, bsums, n, row, cur);
    fill_kernel<<<nb_e, NTH, 0, stream>>>(src, dst, E, cur, csr);

    // layer 1: aggregate x (16ch) then transform 16->32
    float* xs1 = buf1;  // 16n
    float* ga1 = buf2;  // 16n
    float* h1  = buf3;  // 32n
    float* xs2 = buf1;  // 32n (after xs1 dead)
    prescale16_kernel<<<(n * 4 + NTH - 1) / NTH, NTH, 0, stream>>>(x, dinv, xs1, n);
    gather_kernel<16, false><<<(n + 63) / 64, NTH, 0, stream>>>(row, csr, xs1, x, dinv, invdeg, nullptr, ga1, n);
    transform_kernel<16, 32, true, true><<<nb_n, NTH, 0, stream>>>(ga1, W1, b1, dinv, h1, xs2, n);

    // layer 2: aggregate h1 (32ch) then transform 32->64
    float* ga2 = buf2;  // 32n
    float* h2  = buf1;  // 64n (xs2 dead after gather)
    gather_kernel<32, false><<<(n + 31) / 32, NTH, 0, stream>>>(row, csr, xs2, h1, dinv, invdeg, nullptr, ga2, n);
    transform_kernel<32, 64, true, false><<<nb_n, NTH, 0, stream>>>(ga2, W2, b2, dinv, h2, nullptr, n);

    // layer 3: transform 64->32 first (t3, ts3), aggregate post-transform, fuse b3+relu
    float* t3  = buf2;                  // 32n
    float* ts3 = buf2 + (size_t)32 * n; // 32n
    float* h3  = buf3;                  // 32n (h1 dead)
    transform_kernel<64, 32, false, true><<<nb_n, NTH, 0, stream>>>(h2, W3, nullptr, dinv, t3, ts3, n);
    gather_kernel<32, true><<<(n + 31) / 32, NTH, 0, stream>>>(row, csr, ts3, t3, dinv, invdeg, b3, h3, n);

    // MLP head: 32 -> 1024 -> 1
    dim3 mgrid(nb_n, 4);
    mlp_partial_kernel<<<mgrid, NTH, 0, stream>>>(h3, Wf1, bf1, Wf2, accml, n);
    sigmoid_kernel<<<nb_n, NTH, 0, stream>>>(accml, bf2, out, n);
}

// Round 4
// 248.875 us; speedup vs baseline: 6.0447x; 1.1159x over previous
//
#include <hip/hip_runtime.h>
#include <math.h>

#define C_IN 16
#define NTH 256

// ---------------- degree count (int) ----------------
__global__ __launch_bounds__(NTH) void count_kernel(const int* __restrict__ dst, int E,
                                                    int* __restrict__ cnt) {
    int e = blockIdx.x * NTH + threadIdx.x;
    if (e < E) atomicAdd(&cnt[dst[e]], 1);
}

__global__ __launch_bounds__(NTH) void dinv_kernel(const int* __restrict__ cnt,
                                                   float* __restrict__ dinv,
                                                   float* __restrict__ invdeg, int n) {
    int i = blockIdx.x * NTH + threadIdx.x;
    if (i < n) {
        float d = (float)cnt[i] + 1.0f;
        dinv[i] = rsqrtf(d);
        invdeg[i] = 1.0f / d;
    }
}

// ---------------- 3-pass exclusive scan over cnt -> row_ptr, cursor ----------------
__global__ __launch_bounds__(NTH) void scan1_kernel(const int* __restrict__ cnt, int n,
                                                    int* __restrict__ bsum) {
    __shared__ int s[NTH];
    int i = blockIdx.x * NTH + threadIdx.x;
    s[threadIdx.x] = (i < n) ? cnt[i] : 0;
    __syncthreads();
    for (int off = NTH / 2; off > 0; off >>= 1) {
        if (threadIdx.x < off) s[threadIdx.x] += s[threadIdx.x + off];
        __syncthreads();
    }
    if (threadIdx.x == 0) bsum[blockIdx.x] = s[0];
}

__global__ __launch_bounds__(NTH) void scan2_kernel(int* __restrict__ bsum, int nb) {
    __shared__ int s[NTH];
    int base = 0;
    for (int c = 0; c < nb; c += NTH) {
        int idx = c + threadIdx.x;
        int v = (idx < nb) ? bsum[idx] : 0;
        s[threadIdx.x] = v;
        __syncthreads();
        for (int off = 1; off < NTH; off <<= 1) {
            int x = (threadIdx.x >= off) ? s[threadIdx.x - off] : 0;
            __syncthreads();
            s[threadIdx.x] += x;
            __syncthreads();
        }
        if (idx < nb) bsum[idx] = base + s[threadIdx.x] - v;  // exclusive
        int tot = s[NTH - 1];
        __syncthreads();
        base += tot;
    }
}

__global__ __launch_bounds__(NTH) void scan3_kernel(const int* __restrict__ cnt,
                                                    const int* __restrict__ bsum, int n,
                                                    int* __restrict__ row,
                                                    int* __restrict__ cur) {
    __shared__ int s[NTH];
    int i = blockIdx.x * NTH + threadIdx.x;
    int v = (i < n) ? cnt[i] : 0;
    s[threadIdx.x] = v;
    __syncthreads();
    for (int off = 1; off < NTH; off <<= 1) {
        int x = (threadIdx.x >= off) ? s[threadIdx.x - off] : 0;
        __syncthreads();
        s[threadIdx.x] += x;
        __syncthreads();
    }
    if (i < n) {
        int excl = bsum[blockIdx.x] + s[threadIdx.x] - v;
        row[i] = excl;
        cur[i] = excl;
        if (i == n - 1) row[n] = excl + v;
    }
}

__global__ __launch_bounds__(NTH) void fill_kernel(const int* __restrict__ src,
                                                   const int* __restrict__ dst, int E,
                                                   int* __restrict__ cur,
                                                   int* __restrict__ csr) {
    int e = blockIdx.x * NTH + threadIdx.x;
    if (e < E) {
        int p = atomicAdd(&cur[dst[e]], 1);
        csr[p] = src[e];
    }
}

// ---------------- prescale: xs = x * dinv[i]  (C=16, one float4/thread) ----------------
__global__ __launch_bounds__(NTH) void prescale16_kernel(const float* __restrict__ x,
                                                         const float* __restrict__ dinv,
                                                         float* __restrict__ xs, int n) {
    int idx = blockIdx.x * NTH + threadIdx.x;   // float4 index; 4 per node
    if (idx >= n * 4) return;
    int i = idx >> 2;
    float4 v = reinterpret_cast<const float4*>(x)[idx];
    float d = dinv[i];
    v.x *= d; v.y *= d; v.z *= d; v.w *= d;
    reinterpret_cast<float4*>(xs)[idx] = v;
}

// ---------------- CSR gather: out[i] = dinv[i]*sum xs[src] + invdeg[i]*self[i] (+b, relu) --
template<int C, bool FINAL>
__global__ __launch_bounds__(NTH) void gather_kernel(const int* __restrict__ row,
                                                     const int* __restrict__ csr,
                                                     const float* __restrict__ xs,
                                                     const float* __restrict__ self,
                                                     const float* __restrict__ dinv,
                                                     const float* __restrict__ invdeg,
                                                     const float* __restrict__ bias,
                                                     float* __restrict__ out, int n) {
    constexpr int G = C / 4;                    // threads per node
    int i = blockIdx.x * (NTH / G) + threadIdx.x / G;
    int q = threadIdx.x % G;
    if (i >= n) return;
    int r0 = row[i], r1 = row[i + 1];
    float4 acc = make_float4(0.f, 0.f, 0.f, 0.f);
    int e = r0;
    // 4-wide unroll: 4 independent random loads in flight (latency-bound on L2/LLC)
    for (; e + 3 < r1; e += 4) {
        int s0 = csr[e], s1 = csr[e + 1], s2 = csr[e + 2], s3 = csr[e + 3];
        float4 v0 = *reinterpret_cast<const float4*>(xs + (size_t)s0 * C + q * 4);
        float4 v1 = *reinterpret_cast<const float4*>(xs + (size_t)s1 * C + q * 4);
        float4 v2 = *reinterpret_cast<const float4*>(xs + (size_t)s2 * C + q * 4);
        float4 v3 = *reinterpret_cast<const float4*>(xs + (size_t)s3 * C + q * 4);
        acc.x += (v0.x + v1.x) + (v2.x + v3.x);
        acc.y += (v0.y + v1.y) + (v2.y + v3.y);
        acc.z += (v0.z + v1.z) + (v2.z + v3.z);
        acc.w += (v0.w + v1.w) + (v2.w + v3.w);
    }
    for (; e < r1; ++e) {
        int s0 = csr[e];
        float4 v0 = *reinterpret_cast<const float4*>(xs + (size_t)s0 * C + q * 4);
        acc.x += v0.x; acc.y += v0.y; acc.z += v0.z; acc.w += v0.w;
    }
    float di = dinv[i], idg = invdeg[i];
    float4 sv = *reinterpret_cast<const float4*>(self + (size_t)i * C + q * 4);
    float4 o;
    o.x = fmaf(acc.x, di, sv.x * idg);
    o.y = fmaf(acc.y, di, sv.y * idg);
    o.z = fmaf(acc.z, di, sv.z * idg);
    o.w = fmaf(acc.w, di, sv.w * idg);
    if (FINAL) {
        const float4 b = *reinterpret_cast<const float4*>(bias + q * 4);
        o.x = fmaxf(o.x + b.x, 0.f);
        o.y = fmaxf(o.y + b.y, 0.f);
        o.z = fmaxf(o.z + b.z, 0.f);
        o.w = fmaxf(o.w + b.w, 0.f);
    }
    *reinterpret_cast<float4*>(out + (size_t)i * C + q * 4) = o;
}

// ---------------- dense transform: h = [relu](g @ W + b); optional hsc = h * dinv ------
template<int CIN, int COUT, bool BIASRELU, bool WSC>
__global__ __launch_bounds__(NTH) void transform_kernel(const float* __restrict__ g,
                                                        const float* __restrict__ W,
                                                        const float* __restrict__ b,
                                                        const float* __restrict__ dinv,
                                                        float* __restrict__ h,
                                                        float* __restrict__ hsc, int n) {
    __shared__ float Ws[CIN * COUT];
    __shared__ float bs[COUT];
    for (int idx = threadIdx.x; idx < CIN * COUT; idx += NTH) Ws[idx] = W[idx];
    if (BIASRELU && threadIdx.x < COUT) bs[threadIdx.x] = b[threadIdx.x];
    __syncthreads();

    int i = blockIdx.x * NTH + threadIdx.x;
    if (i >= n) return;

    float xr[CIN];
    const float4* xv = reinterpret_cast<const float4*>(g + (size_t)i * CIN);
    #pragma unroll
    for (int k4 = 0; k4 < CIN / 4; ++k4) {
        float4 v = xv[k4];
        xr[k4*4+0] = v.x; xr[k4*4+1] = v.y; xr[k4*4+2] = v.z; xr[k4*4+3] = v.w;
    }

    float di = WSC ? dinv[i] : 0.f;
    float4* hv = reinterpret_cast<float4*>(h + (size_t)i * COUT);
    float4* hscv = WSC ? reinterpret_cast<float4*>(hsc + (size_t)i * COUT) : nullptr;

    #pragma unroll 1
    for (int c4 = 0; c4 < COUT / 4; ++c4) {
        float a0 = 0.f, a1 = 0.f, a2 = 0.f, a3 = 0.f;
        #pragma unroll
        for (int k = 0; k < CIN; ++k) {
            const float4 w = *reinterpret_cast<const float4*>(&Ws[k * COUT + c4 * 4]);
            float xk = xr[k];
            a0 = fmaf(xk, w.x, a0);
            a1 = fmaf(xk, w.y, a1);
            a2 = fmaf(xk, w.z, a2);
            a3 = fmaf(xk, w.w, a3);
        }
        if (BIASRELU) {
            const float4 bv = *reinterpret_cast<const float4*>(&bs[c4 * 4]);
            a0 = fmaxf(a0 + bv.x, 0.f);
            a1 = fmaxf(a1 + bv.y, 0.f);
            a2 = fmaxf(a2 + bv.z, 0.f);
            a3 = fmaxf(a3 + bv.w, 0.f);
        }
        float4 o; o.x = a0; o.y = a1; o.z = a2; o.w = a3;
        hv[c4] = o;
        if (WSC) {
            float4 s; s.x = a0 * di; s.y = a1 * di; s.z = a2 * di; s.w = a3 * di;
            hscv[c4] = s;
        }
    }
}

// ---------------- MLP head: 2 nodes/thread, JC=128, 8-way j-split, deterministic partials --
__global__ __launch_bounds__(NTH, 2) void mlp_partial_kernel(const float* __restrict__ h3,
                                                             const float* __restrict__ Wf1,
                                                             const float* __restrict__ bf1,
                                                             const float* __restrict__ Wf2,
                                                             float* __restrict__ part, int n) {
    constexpr int JC = 128;
    __shared__ float Wl[32 * JC];     // 16 KB, [k][jj] k-major
    __shared__ float b1s[JC];
    __shared__ float w2s[JC];
    const int j0 = blockIdx.y * JC;

    for (int idx = threadIdx.x; idx < 32 * JC; idx += NTH) {
        int k = idx >> 7, jj = idx & (JC - 1);
        Wl[idx] = Wf1[k * 1024 + j0 + jj];
    }
    if (threadIdx.x < JC) {
        b1s[threadIdx.x] = bf1[j0 + threadIdx.x];
        w2s[threadIdx.x] = Wf2[j0 + threadIdx.x];
    }
    __syncthreads();

    const int i0 = blockIdx.x * (2 * NTH) + threadIdx.x;
    const int i1 = i0 + NTH;
    const bool v0 = i0 < n, v1 = i1 < n;

    float t0[32], t1[32];
    if (v0) {
        const float4* av = reinterpret_cast<const float4*>(h3 + (size_t)i0 * 32);
        #pragma unroll
        for (int k4 = 0; k4 < 8; ++k4) {
            float4 v = av[k4];
            t0[k4*4+0] = v.x; t0[k4*4+1] = v.y; t0[k4*4+2] = v.z; t0[k4*4+3] = v.w;
        }
    } else {
        #pragma unroll
        for (int k = 0; k < 32; ++k) t0[k] = 0.f;
    }
    if (v1) {
        const float4* av = reinterpret_cast<const float4*>(h3 + (size_t)i1 * 32);
        #pragma unroll
        for (int k4 = 0; k4 < 8; ++k4) {
            float4 v = av[k4];
            t1[k4*4+0] = v.x; t1[k4*4+1] = v.y; t1[k4*4+2] = v.z; t1[k4*4+3] = v.w;
        }
    } else {
        #pragma unroll
        for (int k = 0; k < 32; ++k) t1[k] = 0.f;
    }

    float a0 = 0.f, a1 = 0.f;
    #pragma unroll 1
    for (int jj = 0; jj < JC; jj += 4) {
        const float4 bv = *reinterpret_cast<const float4*>(&b1s[jj]);
        float s00 = bv.x, s01 = bv.y, s02 = bv.z, s03 = bv.w;
        float s10 = bv.x, s11 = bv.y, s12 = bv.z, s13 = bv.w;
        #pragma unroll
        for (int k = 0; k < 32; ++k) {
            const float4 w = *reinterpret_cast<const float4*>(&Wl[k * JC + jj]);
            float u = t0[k], v = t1[k];
            s00 = fmaf(u, w.x, s00);
            s01 = fmaf(u, w.y, s01);
            s02 = fmaf(u, w.z, s02);
            s03 = fmaf(u, w.w, s03);
            s10 = fmaf(v, w.x, s10);
            s11 = fmaf(v, w.y, s11);
            s12 = fmaf(v, w.z, s12);
            s13 = fmaf(v, w.w, s13);
        }
        const float4 w2 = *reinterpret_cast<const float4*>(&w2s[jj]);
        a0 = fmaf(fmaxf(s00, 0.f), w2.x, a0);
        a0 = fmaf(fmaxf(s01, 0.f), w2.y, a0);
        a0 = fmaf(fmaxf(s02, 0.f), w2.z, a0);
        a0 = fmaf(fmaxf(s03, 0.f), w2.w, a0);
        a1 = fmaf(fmaxf(s10, 0.f), w2.x, a1);
        a1 = fmaf(fmaxf(s11, 0.f), w2.y, a1);
        a1 = fmaf(fmaxf(s12, 0.f), w2.z, a1);
        a1 = fmaf(fmaxf(s13, 0.f), w2.w, a1);
    }
    float* slice = part + (size_t)blockIdx.y * n;
    if (v0) slice[i0] = a0;
    if (v1) slice[i1] = a1;
}

__global__ __launch_bounds__(NTH) void sigmoid_kernel(const float* __restrict__ part,
                                                      const float* __restrict__ bf2,
                                                      float* __restrict__ out, int n) {
    int i = blockIdx.x * NTH + threadIdx.x;
    if (i < n) {
        float z = bf2[0];
        #pragma unroll
        for (int s = 0; s < 8; ++s) z += part[(size_t)s * n + i];
        out[i] = 1.0f / (1.0f + expf(-z));
    }
}

extern "C" void kernel_launch(void* const* d_in, const int* in_sizes, int n_in,
                              void* d_out, int out_size, void* d_ws, size_t ws_size,
                              hipStream_t stream) {
    const float* x    = (const float*)d_in[0];
    const int*   ei   = (const int*)d_in[1];
    const float* W1   = (const float*)d_in[2];
    const float* b1   = (const float*)d_in[3];
    const float* W2   = (const float*)d_in[4];
    const float* b2   = (const float*)d_in[5];
    const float* W3   = (const float*)d_in[6];
    const float* b3   = (const float*)d_in[7];
    const float* Wf1  = (const float*)d_in[8];
    const float* bf1  = (const float*)d_in[9];
    const float* Wf2  = (const float*)d_in[10];
    const float* bf2  = (const float*)d_in[11];
    float* out = (float*)d_out;

    const int n = in_sizes[0] / C_IN;          // 50000
    const int E = in_sizes[1] / 2;             // 800000
    const int* src = ei;
    const int* dst = ei + E;

    // ---- workspace layout ----
    float* ws = (float*)d_ws;
    float* dinv   = ws;                          // [n]
    float* invdeg = ws + (size_t)n;              // [n]
    float* part   = ws + (size_t)2 * n;          // [8n]
    float* buf1   = ws + (size_t)10 * n;         // [64n]
    float* buf2   = ws + (size_t)74 * n;         // [64n]
    float* buf3   = ws + (size_t)138 * n;        // [32n]
    int*   iw     = (int*)(ws + (size_t)170 * n);
    int*   cnt    = iw;                          // [n]
    int*   row    = iw + (size_t)n;              // [n+1]
    int*   cur    = iw + (size_t)2 * n + 1;      // [n]
    int*   csr    = iw + (size_t)3 * n + 1;      // [E]
    int*   bsums  = iw + (size_t)3 * n + 1 + E;  // [nb_n] — disjoint from cur
    (void)ws_size; (void)n_in; (void)out_size;

    const int nb_n = (n + NTH - 1) / NTH;        // 196
    const int nb_e = (E + NTH - 1) / NTH;        // 3125

    hipMemsetAsync(cnt, 0, (size_t)n * sizeof(int), stream);

    // degree + CSR build
    count_kernel<<<nb_e, NTH, 0, stream>>>(dst, E, cnt);
    dinv_kernel<<<nb_n, NTH, 0, stream>>>(cnt, dinv, invdeg, n);
    scan1_kernel<<<nb_n, NTH, 0, stream>>>(cnt, n, bsums);
    scan2_kernel<<<1, NTH, 0, stream>>>(bsums, nb_n);
    scan3_kernel<<<nb_n, NTH, 0, stream>>>(cnt, bsums, n, row, cur);
    fill_kernel<<<nb_e, NTH, 0, stream>>>(src, dst, E, cur, csr);

    // layer 1: aggregate x (16ch) then transform 16->32
    float* xs1 = buf1;  // 16n
    float* ga1 = buf2;  // 16n
    float* h1  = buf3;  // 32n
    float* xs2 = buf1;  // 32n (after xs1 dead)
    prescale16_kernel<<<(n * 4 + NTH - 1) / NTH, NTH, 0, stream>>>(x, dinv, xs1, n);
    gather_kernel<16, false><<<(n + 63) / 64, NTH, 0, stream>>>(row, csr, xs1, x, dinv, invdeg, nullptr, ga1, n);
    transform_kernel<16, 32, true, true><<<nb_n, NTH, 0, stream>>>(ga1, W1, b1, dinv, h1, xs2, n);

    // layer 2: aggregate h1 (32ch) then transform 32->64
    float* ga2 = buf2;  // 32n
    float* h2  = buf1;  // 64n (xs2 dead after gather)
    gather_kernel<32, false><<<(n + 31) / 32, NTH, 0, stream>>>(row, csr, xs2, h1, dinv, invdeg, nullptr, ga2, n);
    transform_kernel<32, 64, true, false><<<nb_n, NTH, 0, stream>>>(ga2, W2, b2, dinv, h2, nullptr, n);

    // layer 3: transform 64->32 first (t3, ts3), aggregate post-transform, fuse b3+relu
    float* t3  = buf2;                  // 32n
    float* ts3 = buf2 + (size_t)32 * n; // 32n
    float* h3  = buf3;                  // 32n (h1 dead)
    transform_kernel<64, 32, false, true><<<nb_n, NTH, 0, stream>>>(h2, W3, nullptr, dinv, t3, ts3, n);
    gather_kernel<32, true><<<(n + 31) / 32, NTH, 0, stream>>>(row, csr, ts3, t3, dinv, invdeg, b3, h3, n);

    // MLP head: 32 -> 1024 -> 1, 2 nodes/thread, 8-way j-split, deterministic partials
    dim3 mgrid((n + 2 * NTH - 1) / (2 * NTH), 8);
    mlp_partial_kernel<<<mgrid, NTH, 0, stream>>>(h3, Wf1, bf1, Wf2, part, n);
    sigmoid_kernel<<<nb_n, NTH, 0, stream>>>(part, bf2, out, n);
}